// Round 18
// baseline (866.820 us; speedup 1.0000x reference)
//
#include <hip/hip_runtime.h>
#include <cmath>

typedef __bf16 bf16;
typedef __attribute__((ext_vector_type(8))) __bf16 bf16x8;
typedef __attribute__((ext_vector_type(4))) __bf16 bf16x4v;
typedef __attribute__((ext_vector_type(4))) float f32x4;
typedef __attribute__((ext_vector_type(2))) unsigned int u32x2;

constexpr int NROWS = 512 * 127;                 // 65024
constexpr float LR = 0.01f;
constexpr float INV_NU = 1.f / (65024.f * 256.f);

// fast (sigmoid) gelu family — |err| < 2e-3 on |x|<1; 27x margin vs threshold.
__device__ __forceinline__ float sigf(float x) {
  return 1.f / (1.f + __expf(-1.702f * x));
}
__device__ __forceinline__ float gelu_fast(float x) { return x * sigf(x); }
__device__ __forceinline__ float dgelu_fast(float x) {
  float s = sigf(x);
  return s * (1.f + 1.702f * x * (1.f - s));
}
__device__ __forceinline__ bf16x8 gelu8f(bf16x8 v) {
  bf16x8 o;
#pragma unroll
  for (int i = 0; i < 8; i++) o[i] = (bf16)gelu_fast((float)v[i]);
  return o;
}

// async global->LDS, 16B per lane, wave-uniform LDS base
__device__ __forceinline__ void gload16(const bf16* g, const bf16* lds) {
  __builtin_amdgcn_global_load_lds(
      (const __attribute__((address_space(1))) unsigned int*)(size_t)(const void*)g,
      (__attribute__((address_space(3))) unsigned int*)(unsigned)(size_t)(const void*)lds,
      16, 0, 0);
}

// XCD chunked-bijective swizzle of the linearized block id (T1).
__device__ __forceinline__ int xcd_lin() {
  int p = ((int)blockIdx.z * (int)gridDim.y + (int)blockIdx.y) * (int)gridDim.x + (int)blockIdx.x;
  const int total = (int)gridDim.x * (int)gridDim.y * (int)gridDim.z;
  if (!(total & 7)) p = (p & 7) * (total >> 3) + (p >> 3);
  return p;
}

// ---------------------------------------------------------------------------
// gemm6: 128x128 tile, BK=32, launch_bounds(256,4) -> total regs <= 128,
// 4 waves/SIMD + 32 KB LDS -> 4 blocks/CU. Double-buffered global_load_lds,
// counted vmcnt(4), XCD swizzle, operand-swapped MFMA -> x4 vector epilogue.
// EPI: 0=f32, 1=bf16, 2=dgelu->out0+gelu->out1, 3=gelu, 5=acc*dgelu(aux),
//      6=acc*aux, 7=f32 out0 + bf16 out1, 8=bf16(acc + f32 aux)
// ---------------------------------------------------------------------------
template <int EPI>
__global__ __launch_bounds__(256, 4) void gemm6_k(
    const bf16* __restrict__ A, const bf16* __restrict__ Bt,
    const float* __restrict__ bias, void* __restrict__ out0,
    void* __restrict__ out1, const bf16* __restrict__ aux,
    int M, int N, int K) {
  __shared__ __align__(16) bf16 As[2][128 * 32];
  __shared__ __align__(16) bf16 Bs[2][128 * 32];
  const int t = threadIdx.x;
  const int p = xcd_lin();
  const int bn = (p % (int)gridDim.x) * 128;
  const int bm = (p / (int)gridDim.x) * 128;
  const int lane = t & 63, w = t >> 6;
  const int wr = w >> 1, wc = w & 1;

  f32x4 acc[4][4];
#pragma unroll
  for (int mi = 0; mi < 4; mi++)
#pragma unroll
    for (int ni = 0; ni < 4; ni++) {
      f32x4 z = {0.f, 0.f, 0.f, 0.f};
      acc[mi][ni] = z;
    }

  const int lr = lane >> 2;
  const int csw = (lane & 3) ^ (lr & 3);
  const bf16* aBase = A + (size_t)(bm + 32 * w + lr) * K + csw * 8;
  const bf16* bBase = Bt + (size_t)(bn + 32 * w + lr) * K + csw * 8;

  const int ml = lane & 15, g = lane >> 4;
  const int c0 = g ^ (ml & 3);

  const int nt = K >> 5;
#pragma unroll
  for (int i = 0; i < 2; i++) {
    gload16(aBase + (size_t)(16 * i) * K, As[0] + (32 * w + 16 * i) * 32);
    gload16(bBase + (size_t)(16 * i) * K, Bs[0] + (32 * w + 16 * i) * 32);
  }

  for (int tt = 0; tt < nt; tt++) {
    const int cur = tt & 1;
    if (tt + 1 < nt) {
      const int ko = (tt + 1) * 32;
#pragma unroll
      for (int i = 0; i < 2; i++) {
        gload16(aBase + (size_t)(16 * i) * K + ko, As[cur ^ 1] + (32 * w + 16 * i) * 32);
        gload16(bBase + (size_t)(16 * i) * K + ko, Bs[cur ^ 1] + (32 * w + 16 * i) * 32);
      }
      asm volatile("s_waitcnt vmcnt(4)" ::: "memory");
    } else {
      asm volatile("s_waitcnt vmcnt(0)" ::: "memory");
    }
    __builtin_amdgcn_s_barrier();
    __builtin_amdgcn_sched_barrier(0);

    bf16x8 af[4], bfr[4];
#pragma unroll
    for (int mi = 0; mi < 4; mi++) {
      const int m = wr * 64 + mi * 16 + ml;
      const int n = wc * 64 + mi * 16 + ml;
      af[mi] = *(const bf16x8*)&As[cur][m * 32 + c0 * 8];
      bfr[mi] = *(const bf16x8*)&Bs[cur][n * 32 + c0 * 8];
    }
#pragma unroll
    for (int mi = 0; mi < 4; mi++)
#pragma unroll
      for (int ni = 0; ni < 4; ni++)
        acc[mi][ni] = __builtin_amdgcn_mfma_f32_16x16x32_bf16(
            bfr[ni], af[mi], acc[mi][ni], 0, 0, 0);
    __builtin_amdgcn_s_barrier();
  }

  const int g4 = (lane >> 4) << 2;
#pragma unroll
  for (int mi = 0; mi < 4; mi++) {
    const int m = bm + wr * 64 + mi * 16 + ml;
#pragma unroll
    for (int ni = 0; ni < 4; ni++) {
      const int n0 = bn + wc * 64 + ni * 16 + g4;
      f32x4 v = acc[mi][ni];
      if (bias) {
        const float4 bv = *(const float4*)(bias + n0);
        v[0] += bv.x; v[1] += bv.y; v[2] += bv.z; v[3] += bv.w;
      }
      const size_t idx = (size_t)m * N + n0;
      if constexpr (EPI == 0) {
        *(float4*)((float*)out0 + idx) = make_float4(v[0], v[1], v[2], v[3]);
      } else if constexpr (EPI == 1) {
        bf16x4v o;
#pragma unroll
        for (int j = 0; j < 4; j++) o[j] = (bf16)v[j];
        *(bf16x4v*)((bf16*)out0 + idx) = o;
      } else if constexpr (EPI == 2) {
        bf16x4v od, oh;
#pragma unroll
        for (int j = 0; j < 4; j++) {
          float s = sigf(v[j]);
          oh[j] = (bf16)(v[j] * s);
          od[j] = (bf16)(s * (1.f + 1.702f * v[j] * (1.f - s)));
        }
        *(bf16x4v*)((bf16*)out0 + idx) = od;
        *(bf16x4v*)((bf16*)out1 + idx) = oh;
      } else if constexpr (EPI == 3) {
        bf16x4v o;
#pragma unroll
        for (int j = 0; j < 4; j++) o[j] = (bf16)gelu_fast(v[j]);
        *(bf16x4v*)((bf16*)out0 + idx) = o;
      } else if constexpr (EPI == 5) {
        const bf16x4v a4 = *(const bf16x4v*)(aux + idx);
        bf16x4v o;
#pragma unroll
        for (int j = 0; j < 4; j++) o[j] = (bf16)(v[j] * dgelu_fast((float)a4[j]));
        *(bf16x4v*)((bf16*)out0 + idx) = o;
      } else if constexpr (EPI == 6) {
        const bf16x4v a4 = *(const bf16x4v*)(aux + idx);
        bf16x4v o;
#pragma unroll
        for (int j = 0; j < 4; j++) o[j] = (bf16)(v[j] * (float)a4[j]);
        *(bf16x4v*)((bf16*)out0 + idx) = o;
      } else if constexpr (EPI == 7) {
        *(float4*)((float*)out0 + idx) = make_float4(v[0], v[1], v[2], v[3]);
        bf16x4v o;
#pragma unroll
        for (int j = 0; j < 4; j++) o[j] = (bf16)v[j];
        *(bf16x4v*)((bf16*)out1 + idx) = o;
      } else {   // EPI 8
        const float4 c4 = *(const float4*)((const float*)aux + idx);
        bf16x4v o;
        o[0] = (bf16)(v[0] + c4.x); o[1] = (bf16)(v[1] + c4.y);
        o[2] = (bf16)(v[2] + c4.z); o[3] = (bf16)(v[3] + c4.w);
        *(bf16x4v*)((bf16*)out0 + idx) = o;
      }
    }
  }
}

// ---------------------------------------------------------------------------
// gemm7: gemm6 structure, A reg-staged with fast-gelu applied once at the
// write-late LDS store. B keeps global_load_lds. Used for z = gelu(a1)@Wzg.
// ---------------------------------------------------------------------------
template <int EPI>
__global__ __launch_bounds__(256, 4) void gemm7_k(
    const bf16* __restrict__ A, const bf16* __restrict__ Bt,
    const float* __restrict__ bias, void* __restrict__ out0,
    void* __restrict__ out1, const bf16* __restrict__ aux,
    int M, int N, int K) {
  __shared__ __align__(16) bf16 As[2][128 * 32];
  __shared__ __align__(16) bf16 Bs[2][128 * 32];
  const int t = threadIdx.x;
  const int p = xcd_lin();
  const int bn = (p % (int)gridDim.x) * 128;
  const int bm = (p / (int)gridDim.x) * 128;
  const int lane = t & 63, w = t >> 6;
  const int wr = w >> 1, wc = w & 1;

  f32x4 acc[4][4];
#pragma unroll
  for (int mi = 0; mi < 4; mi++)
#pragma unroll
    for (int ni = 0; ni < 4; ni++) {
      f32x4 z = {0.f, 0.f, 0.f, 0.f};
      acc[mi][ni] = z;
    }

  const int lr = lane >> 2;
  const int csw = (lane & 3) ^ (lr & 3);
  const bf16* aBase = A + (size_t)(bm + 32 * w + lr) * K + csw * 8;
  const bf16* bBase = Bt + (size_t)(bn + 32 * w + lr) * K + csw * 8;
  const int awoff = (32 * w + lr) * 32 + (lane & 3) * 8;

  const int ml = lane & 15, g = lane >> 4;
  const int c0 = g ^ (ml & 3);

  const int nt = K >> 5;
  {
    bf16x8 av0 = *(const bf16x8*)aBase;
    bf16x8 av1 = *(const bf16x8*)(aBase + (size_t)16 * K);
    gload16(bBase, Bs[0] + (32 * w) * 32);
    gload16(bBase + (size_t)16 * K, Bs[0] + (32 * w + 16) * 32);
    *(bf16x8*)&As[0][awoff] = gelu8f(av0);
    *(bf16x8*)&As[0][awoff + 512] = gelu8f(av1);
  }
  __syncthreads();

  bf16x8 av0, av1;
  for (int tt = 0; tt < nt; tt++) {
    const int cur = tt & 1;
    if (tt + 1 < nt) {
      const int ko = (tt + 1) * 32;
      gload16(bBase + ko, Bs[cur ^ 1] + (32 * w) * 32);
      gload16(bBase + (size_t)16 * K + ko, Bs[cur ^ 1] + (32 * w + 16) * 32);
      av0 = *(const bf16x8*)(aBase + ko);
      av1 = *(const bf16x8*)(aBase + (size_t)16 * K + ko);
    }

    bf16x8 af[4], bfr[4];
#pragma unroll
    for (int mi = 0; mi < 4; mi++) {
      const int m = wr * 64 + mi * 16 + ml;
      const int n = wc * 64 + mi * 16 + ml;
      af[mi] = *(const bf16x8*)&As[cur][m * 32 + c0 * 8];
      bfr[mi] = *(const bf16x8*)&Bs[cur][n * 32 + c0 * 8];
    }
#pragma unroll
    for (int mi = 0; mi < 4; mi++)
#pragma unroll
      for (int ni = 0; ni < 4; ni++)
        acc[mi][ni] = __builtin_amdgcn_mfma_f32_16x16x32_bf16(
            bfr[ni], af[mi], acc[mi][ni], 0, 0, 0);

    if (tt + 1 < nt) {
      *(bf16x8*)&As[cur ^ 1][awoff] = gelu8f(av0);
      *(bf16x8*)&As[cur ^ 1][awoff + 512] = gelu8f(av1);
    }
    __syncthreads();
  }

  const int g4 = (lane >> 4) << 2;
#pragma unroll
  for (int mi = 0; mi < 4; mi++) {
    const int m = bm + wr * 64 + mi * 16 + ml;
#pragma unroll
    for (int ni = 0; ni < 4; ni++) {
      const int n0 = bn + wc * 64 + ni * 16 + g4;
      f32x4 v = acc[mi][ni];
      if (bias) {
        const float4 bv = *(const float4*)(bias + n0);
        v[0] += bv.x; v[1] += bv.y; v[2] += bv.z; v[3] += bv.w;
      }
      const size_t idx = (size_t)m * N + n0;
      if constexpr (EPI == 0) {
        *(float4*)((float*)out0 + idx) = make_float4(v[0], v[1], v[2], v[3]);
      } else {
        bf16x4v o;
#pragma unroll
        for (int j = 0; j < 4; j++) o[j] = (bf16)v[j];
        *(bf16x4v*)((bf16*)out0 + idx) = o;
      }
    }
  }
}

// ---------------------------------------------------------------------------
// T-GEMM v5: balanced staging — EVERY thread stages 2 A-rows + 2 B-rows
// (t<128 -> row-steps {0,1}, t>=128 -> {2,3}); halves per-thread gelu and
// ds_write burst vs the A/B-half split. LDS layout & tr_b16 read path
// unchanged. Double-buffered, load-early/write-late, XCD swizzle, z=64.
// ---------------------------------------------------------------------------
template <bool GELU_A>
__global__ __launch_bounds__(256) void tgemm5_k(
    const bf16* __restrict__ Asrc, const bf16* __restrict__ Bsrc,
    float* __restrict__ outP, int M, int N, int ldA, int ldB, int K) {
  __shared__ __align__(16) bf16 As[2][4736];
  __shared__ __align__(16) bf16 Bs[2][4736];
  const int t = threadIdx.x;
  const int p = xcd_lin();
  const int gx = (int)gridDim.x, gy = (int)gridDim.y;
  const int bm = (p % gx) * 128;
  const int bn = ((p / gx) % gy) * 128;
  const int zc = p / (gx * gy);
  const int r0 = zc * 1024;
  const int rows = (K - r0 < 1024) ? (K - r0) : 1024;
  const int nt = rows >> 5;
  const int lane = t & 63, w = t >> 6, wr = w >> 1, wc = w & 1;

  f32x4 acc[4][4];
#pragma unroll
  for (int mi = 0; mi < 4; mi++)
#pragma unroll
    for (int ni = 0; ni < 4; ni++) {
      f32x4 z = {0.f, 0.f, 0.f, 0.f};
      acc[mi][ni] = z;
    }

  const int tb = t & 127;
  const int hi = (t >> 7) << 1;            // 0 or 2: which pair of row-steps
  const int srow = tb >> 4;                // 0..7
  const int scol = (tb & 15) * 8;
  const int sms = (tb & 15) >> 1;
  const int shalf = (tb & 1) * 8;
  const int sidx = sms * 592 + srow * 16 + shalf;

  // per-thread A and B source bases (row = srow + (hi+j)*8)
  const bf16* aSrc = Asrc + (size_t)(r0 + srow + hi * 8) * ldA + bm + scol;
  const bf16* bSrc = Bsrc + (size_t)(r0 + srow + hi * 8) * ldB + bn + scol;

  const unsigned abase = (unsigned)(size_t)(void*)As;
  const unsigned bbase = (unsigned)(size_t)(void*)Bs;
  const int g = lane >> 4;
  const int ml = lane & 15;
  const unsigned acol0 = abase + 2u * (unsigned)((wr * 4) * 592 + g * 144 + ml);
  const unsigned bcol0 = bbase + 2u * (unsigned)((wc * 4) * 592 + g * 144 + ml);

  bf16x8 sA0, sA1, sB0, sB1;
  auto ldrows = [&](int kt) {
    sA0 = *(const bf16x8*)(aSrc + (size_t)kt * ldA);
    sA1 = *(const bf16x8*)(aSrc + (size_t)(kt + 8) * ldA);
    sB0 = *(const bf16x8*)(bSrc + (size_t)kt * ldB);
    sB1 = *(const bf16x8*)(bSrc + (size_t)(kt + 8) * ldB);
  };
  auto wrbuf = [&](int buf) {
    bf16x8 a0 = sA0, a1 = sA1;
    if constexpr (GELU_A) { a0 = gelu8f(a0); a1 = gelu8f(a1); }
    *(bf16x8*)&As[buf][sidx + hi * 144] = a0;
    *(bf16x8*)&As[buf][sidx + (hi + 1) * 144] = a1;
    *(bf16x8*)&Bs[buf][sidx + hi * 144] = sB0;
    *(bf16x8*)&Bs[buf][sidx + (hi + 1) * 144] = sB1;
  };

  ldrows(0);
  wrbuf(0);
  __syncthreads();

  for (int tt = 0; tt < nt; tt++) {
    const int cur = tt & 1;
    if (tt + 1 < nt) ldrows((tt + 1) * 32);

    const unsigned boff = (unsigned)cur * (4736u * 2u);
    union FR { u32x2 pr[2]; bf16x8 v; };
    FR af[4], bfr[4];
#pragma unroll
    for (int mi = 0; mi < 4; mi++) {
      const unsigned a = acol0 + boff + (unsigned)(mi * 1184);
      asm volatile("ds_read_b64_tr_b16 %0, %1" : "=v"(af[mi].pr[0]) : "v"(a));
      asm volatile("ds_read_b64_tr_b16 %0, %1 offset:128" : "=v"(af[mi].pr[1]) : "v"(a));
    }
#pragma unroll
    for (int ni = 0; ni < 4; ni++) {
      const unsigned b = bcol0 + boff + (unsigned)(ni * 1184);
      asm volatile("ds_read_b64_tr_b16 %0, %1" : "=v"(bfr[ni].pr[0]) : "v"(b));
      asm volatile("ds_read_b64_tr_b16 %0, %1 offset:128" : "=v"(bfr[ni].pr[1]) : "v"(b));
    }
    asm volatile("s_waitcnt lgkmcnt(0)" ::: "memory");
    __builtin_amdgcn_sched_barrier(0);

#pragma unroll
    for (int mi = 0; mi < 4; mi++)
#pragma unroll
      for (int ni = 0; ni < 4; ni++)
        acc[mi][ni] = __builtin_amdgcn_mfma_f32_16x16x32_bf16(
            bfr[ni].v, af[mi].v, acc[mi][ni], 0, 0, 0);

    if (tt + 1 < nt) wrbuf(cur ^ 1);
    __syncthreads();
  }

  float* o = outP + (size_t)zc * M * N;
  const int g4 = (lane >> 4) << 2;
#pragma unroll
  for (int mi = 0; mi < 4; mi++) {
    const int m = bm + wr * 64 + mi * 16 + ml;
#pragma unroll
    for (int ni = 0; ni < 4; ni++) {
      const int n0 = bn + wc * 64 + ni * 16 + g4;
      f32x4 v = acc[mi][ni];
      *(float4*)(o + (size_t)m * N + n0) = make_float4(v[0], v[1], v[2], v[3]);
    }
  }
}

// ---------------------------------------------------------------------------
__global__ void prep_k(const float* inputs, const float* Wp, const float* Wphi,
                       const float* W1, const float* W2, const float* Wg,
                       const float* Wpsi, const float* Wh,
                       bf16* inb, bf16* WpT, bf16* WphiT, bf16* W1T, bf16* W2T,
                       bf16* WgT, bf16* Wgb, bf16* W2b, bf16* WpsiT, bf16* WhT) {
  int i = blockIdx.x * 256 + threadIdx.x;
  if (i < 65536) {
    inb[i] = (bf16)inputs[i];
  } else if ((i -= 65536) < 32768) {
    int u = i >> 7, f = i & 127;
    WpT[i] = (bf16)Wp[f * 256 + u];
  } else if ((i -= 32768) < 65536) {
    int n = i >> 8, k = i & 255;
    WphiT[i] = (bf16)Wphi[k * 256 + n];
  } else if ((i -= 65536) < 262144) {
    int h = i >> 8, u = i & 255;
    W1T[i] = (bf16)W1[u * 1024 + h];
  } else if ((i -= 262144) < 262144) {
    int u = i >> 10, h = i & 1023;
    W2T[i] = (bf16)W2[h * 256 + u];
  } else if ((i -= 262144) < 65536) {
    int n = i >> 8, k = i & 255;
    WgT[i] = (bf16)Wg[k * 256 + n];
  } else if ((i -= 65536) < 65536) {
    Wgb[i] = (bf16)Wg[i];
  } else if ((i -= 65536) < 262144) {
    W2b[i] = (bf16)W2[i];
  } else if ((i -= 262144) < 65536) {
    int n = i >> 8, k = i & 255;
    WpsiT[i] = (bf16)Wpsi[k * 256 + n];
  } else if ((i -= 65536) < 65536) {
    int n = i >> 8, k = i & 255;
    WhT[i] = (bf16)Wh[k * 256 + n];
  }
}

// bzg[n] = gbias[n] + sum_j b2[j] * Wg[j][n]
__global__ void bzg_k(const float* __restrict__ b2, const float* __restrict__ Wg,
                      const float* __restrict__ gbias, float* __restrict__ bzg) {
  const int n = threadIdx.x;
  float s = gbias[n];
  for (int j = 0; j < 256; j++) s += b2[j] * Wg[j * 256 + n];
  bzg[n] = s;
}

__global__ void xcast_k(const float* __restrict__ seq, bf16* __restrict__ xb) {
  int v8 = blockIdx.x * 256 + threadIdx.x;
  int r = v8 >> 5, c8 = (v8 & 31) * 8;
  int b = r / 127, t = r - b * 127;
  const float* src = seq + ((size_t)(b * 128 + t + 1)) * 256 + c8;
  float4 v0 = *(const float4*)(src);
  float4 v1 = *(const float4*)(src + 4);
  bf16x8 o;
  o[0] = (bf16)v0.x; o[1] = (bf16)v0.y; o[2] = (bf16)v0.z; o[3] = (bf16)v0.w;
  o[4] = (bf16)v1.x; o[5] = (bf16)v1.y; o[6] = (bf16)v1.z; o[7] = (bf16)v1.w;
  *(bf16x8*)(xb + (size_t)r * 256 + c8) = o;
}

__global__ void bufwrite_k(const float* __restrict__ seq, const float* __restrict__ proj,
                           float* __restrict__ buf) {
  int i = blockIdx.x * 256 + threadIdx.x;
  int b = i >> 13, rem = i & 8191;
  int j = rem >> 6, c4 = (rem & 63) * 4;
  float4 v;
  if (j < 127)
    v = *(const float4*)(seq + ((size_t)(b * 128 + j + 1)) * 256 + c4);
  else
    v = *(const float4*)(proj + (size_t)b * 256 + c4);
  *(float4*)(buf + ((size_t)(b * 128 + j)) * 256 + c4) = v;
}

__global__ __launch_bounds__(256) void ln_k(const bf16* zin, bf16* dzout,
                                            const float* __restrict__ seq,
                                            const float* __restrict__ proj,
                                            const float* __restrict__ lng,
                                            const float* __restrict__ lnb,
                                            bf16* __restrict__ rec) {
  const int w = threadIdx.x >> 6, lane = threadIdx.x & 63;
  const int r = blockIdx.x * 4 + w;
  const int b = r / 127, tt = r - b * 127;
  typedef __attribute__((ext_vector_type(4))) __bf16 bf16x4;
  bf16x4 zv = *(const bf16x4*)(zin + (size_t)r * 256 + lane * 4);
  float z0 = (float)zv[0], z1 = (float)zv[1], z2 = (float)zv[2], z3 = (float)zv[3];
  float s1 = z0 + z1 + z2 + z3;
  float s2 = z0 * z0 + z1 * z1 + z2 * z2 + z3 * z3;
  for (int m = 1; m < 64; m <<= 1) { s1 += __shfl_xor(s1, m); s2 += __shfl_xor(s2, m); }
  const float mean = s1 * (1.f / 256.f);
  const float var = s2 * (1.f / 256.f) - mean * mean;
  const float rs = rsqrtf(var + 1e-3f);
  const float4 gv = *(const float4*)(lng + lane * 4);
  const float4 bv = *(const float4*)(lnb + lane * 4);
  const float* ysrc = (tt < 126) ? (seq + ((size_t)(b * 128 + tt + 2)) * 256)
                                 : (proj + (size_t)b * 256);
  const float4 yv = *(const float4*)(ysrc + lane * 4);
  float xh0 = (z0 - mean) * rs, xh1 = (z1 - mean) * rs, xh2 = (z2 - mean) * rs, xh3 = (z3 - mean) * rs;
  float r0 = gv.x * xh0 + bv.x, r1 = gv.y * xh1 + bv.y, r2 = gv.z * xh2 + bv.z, r3 = gv.w * xh3 + bv.w;
  float u0 = 2.f * (r0 - yv.x) * INV_NU * gv.x;
  float u1 = 2.f * (r1 - yv.y) * INV_NU * gv.y;
  float u2 = 2.f * (r2 - yv.z) * INV_NU * gv.z;
  float u3 = 2.f * (r3 - yv.w) * INV_NU * gv.w;
  float t1 = u0 + u1 + u2 + u3;
  float t2 = u0 * xh0 + u1 * xh1 + u2 * xh2 + u3 * xh3;
  for (int m = 1; m < 64; m <<= 1) { t1 += __shfl_xor(t1, m); t2 += __shfl_xor(t2, m); }
  const float mu = t1 * (1.f / 256.f), mux = t2 * (1.f / 256.f);
  bf16x4 ro, dzo;
  ro[0] = (bf16)r0; ro[1] = (bf16)r1; ro[2] = (bf16)r2; ro[3] = (bf16)r3;
  dzo[0] = (bf16)((u0 - mu - xh0 * mux) * rs);
  dzo[1] = (bf16)((u1 - mu - xh1 * mux) * rs);
  dzo[2] = (bf16)((u2 - mu - xh2 * mux) * rs);
  dzo[3] = (bf16)((u3 - mu - xh3 * mux) * rs);
  *(bf16x4*)(rec + (size_t)r * 256 + lane * 4) = ro;
  *(bf16x4*)(dzout + (size_t)r * 256 + lane * 4) = dzo;
}

__global__ void colsum_k(const bf16* __restrict__ src, float* __restrict__ part, int C) {
  const int col = blockIdx.x * 256 + threadIdx.x;
  const int ch = blockIdx.y;
  float s = 0.f;
  const int rbeg = ch * 1016;
  for (int rr = rbeg; rr < rbeg + 1016; rr++) s += (float)src[(size_t)rr * C + col];
  part[(size_t)ch * C + col] = s;
}

__global__ void contrib_k(const bf16* __restrict__ rec, float* __restrict__ contrib) {
  const int b = blockIdx.x, u = threadIdx.x;
  float s = 0.f;
  for (int t = 0; t < 127; t++) s += (float)rec[((size_t)b * 127 + t) * 256 + u];
  contrib[b * 256 + u] = s * (1.f / 127.f);
}

__global__ void update2_k(const float* __restrict__ pW2, const float* __restrict__ pdb2,
                          const float* __restrict__ W2, const float* __restrict__ b2,
                          bf16* __restrict__ W2pT, float* __restrict__ b2p) {
  int idx = blockIdx.x * 256 + threadIdx.x;
  if (idx < 262144) {
    float s = 0.f;
    for (int z = 0; z < 64; z++) s += pW2[(size_t)z * 262144 + idx];
    int h = idx >> 8, u = idx & 255;
    W2pT[(size_t)u * 1024 + h] = (bf16)(W2[idx] - LR * s);
  } else {
    int u = idx - 262144;
    float s = 0.f;
    for (int c = 0; c < 64; c++) s += pdb2[c * 256 + u];
    b2p[u] = b2[u] - LR * s;
  }
}

__global__ void update1_k(const float* __restrict__ pW1, const float* __restrict__ pdb1,
                          const float* __restrict__ W1, const float* __restrict__ b1,
                          bf16* __restrict__ W1pT, float* __restrict__ b1p) {
  int idx = blockIdx.x * 256 + threadIdx.x;
  if (idx < 262144) {
    float s = 0.f;
    for (int z = 0; z < 64; z++) s += pW1[(size_t)z * 262144 + idx];
    int u = idx >> 10, h = idx & 1023;
    W1pT[(size_t)h * 256 + u] = (bf16)(W1[idx] - LR * s);
  } else {
    int h = idx - 262144;
    float s = 0.f;
    for (int c = 0; c < 64; c++) s += pdb1[c * 1024 + h];
    b1p[h] = b1[h] - LR * s;
  }
}

// ---------------------------------------------------------------------------
extern "C" void kernel_launch(void* const* d_in, const int* in_sizes, int n_in,
                              void* d_out, int out_size, void* d_ws, size_t ws_size,
                              hipStream_t stream) {
  const float* inputs = (const float*)d_in[0];
  const float* seq = (const float*)d_in[2];
  const float* Wp = (const float*)d_in[3];
  const float* bp = (const float*)d_in[4];
  const float* Wphi = (const float*)d_in[5];
  const float* bphi = (const float*)d_in[6];
  const float* Wpsi = (const float*)d_in[7];
  const float* bpsi = (const float*)d_in[8];
  const float* W1 = (const float*)d_in[9];
  const float* b1 = (const float*)d_in[10];
  const float* W2 = (const float*)d_in[11];
  const float* b2 = (const float*)d_in[12];
  const float* Wg = (const float*)d_in[13];
  const float* gbias = (const float*)d_in[14];
  const float* lng = (const float*)d_in[15];
  const float* lnb = (const float*)d_in[16];
  const float* Wh = (const float*)d_in[17];
  const float* hbias = (const float*)d_in[18];

  float* out = (float*)d_out;
  float* buf = out + 131072;
  float* pW2 = buf;                          // 64 x 262144 f32 (fills buf)
  float* pW1 = buf;                          // same region, sequential use

  char* wptr = (char*)d_ws;
  auto alloc = [&](size_t bytes) {
    char* p = wptr;
    wptr += (bytes + 255) & ~(size_t)255;
    return p;
  };
  bf16* inb   = (bf16*)alloc(65536 * 2);
  bf16* WpT   = (bf16*)alloc(32768 * 2);
  bf16* WphiT = (bf16*)alloc(65536 * 2);
  bf16* W1T   = (bf16*)alloc(262144 * 2);
  bf16* W2T   = (bf16*)alloc(262144 * 2);
  bf16* WgT   = (bf16*)alloc(65536 * 2);
  bf16* Wgb   = (bf16*)alloc(65536 * 2);
  bf16* W2b   = (bf16*)alloc(262144 * 2);
  bf16* WpsiT = (bf16*)alloc(65536 * 2);
  bf16* WhT   = (bf16*)alloc(65536 * 2);
  bf16* WzgT  = (bf16*)alloc(262144 * 2);
  float* bzg  = (float*)alloc(256 * 4);
  bf16* W1pT  = (bf16*)alloc(262144 * 2);
  bf16* W2pT  = (bf16*)alloc(262144 * 2);
  float* b1p  = (float*)alloc(1024 * 4);
  float* b2p  = (float*)alloc(256 * 4);
  float* proj = (float*)alloc(131072 * 4);
  bf16* projb = (bf16*)alloc(131072 * 2);
  float* pdb2 = (float*)alloc(64 * 256 * 4);
  float* pdb1 = (float*)alloc(64 * 1024 * 4);
  bf16* psib  = (bf16*)alloc(131072 * 2);
  bf16* hpb   = (bf16*)alloc(524288 * 2);
  float* contrib = (float*)alloc(131072 * 4);
  bf16* finb  = (bf16*)alloc(131072 * 2);
  const size_t NU = (size_t)NROWS * 256;
  const size_t NH = (size_t)NROWS * 1024;
  bf16* xz     = (bf16*)alloc(NU * 2);       // x -> z -> dz
  bf16* phi    = (bf16*)alloc(NU * 2);
  bf16* a1b    = (bf16*)alloc(NH * 2);       // a1 -> da1
  bf16* encden = (bf16*)alloc(NU * 2);       // rec -> denc

  // 1. prep weights (+inputs cast)
  prep_k<<<4736, 256, 0, stream>>>(inputs, Wp, Wphi, W1, W2, Wg, Wpsi, Wh,
                                   inb, WpT, WphiT, W1T, W2T, WgT, Wgb, W2b, WpsiT, WhT);
  // 1b. WzgT = Wg^T @ W2^T
  gemm6_k<1><<<dim3(8, 2), 256, 0, stream>>>(WgT, W2b, nullptr, WzgT, nullptr, nullptr, 256, 1024, 256);
  // 1c. bzg = b2 @ Wg + gbias
  bzg_k<<<1, 256, 0, stream>>>(b2, Wg, gbias, bzg);
  // 2. x = bf16(seq shifted)
  xcast_k<<<8128, 256, 0, stream>>>(seq, xz);
  // 3. proj = inputs @ Wp + bp  (f32 + bf16 dual store)
  gemm6_k<7><<<dim3(2, 4), 256, 0, stream>>>(inb, WpT, bp, proj, projb, nullptr, 512, 256, 128);
  // 5. phi = x @ Wphi + bphi
  gemm6_k<1><<<dim3(2, 508), 256, 0, stream>>>(xz, WphiT, bphi, phi, nullptr, nullptr, NROWS, 256, 256);
  // 6. a1 = phi @ W1 + b1   (a1 only; consumers recompute gelu/dgelu)
  gemm6_k<1><<<dim3(8, 508), 256, 0, stream>>>(phi, W1T, b1, a1b, nullptr, nullptr, NROWS, 1024, 256);
  // 7+8 fused. z = gelu(a1) @ (W2@Wg) + bzg   (gelu once in reg staging)
  gemm7_k<1><<<dim3(2, 508), 256, 0, stream>>>(a1b, WzgT, bzg, xz, nullptr, nullptr, NROWS, 256, 1024);
  // 9. LN fwd+bwd: rec -> encden, dz in-place in xz
  ln_k<<<16256, 256, 0, stream>>>(xz, xz, seq, proj, lng, lnb, encden);
  // 10. contrib = mean_t rec
  contrib_k<<<512, 256, 0, stream>>>(encden, contrib);
  // 11. d_enc = dz @ Wg^T (into encden)
  gemm6_k<1><<<dim3(2, 508), 256, 0, stream>>>(xz, Wgb, nullptr, encden, nullptr, nullptr, NROWS, 256, 256);
  // 12. db2 partials
  colsum_k<<<dim3(1, 64), 256, 0, stream>>>(encden, pdb2, 256);
  // 13. dW2 partials = gelu(a1)^T @ d_enc (z=64, balanced staging)
  tgemm5_k<true><<<dim3(8, 2, 64), 256, 0, stream>>>(a1b, encden, pW2, 1024, 256, 1024, 256, NROWS);
  // 14. reduce dW2 + db2
  update2_k<<<1025, 256, 0, stream>>>(pW2, pdb2, W2, b2, W2pT, b2p);
  // 15. d_a1 = (d_enc @ W2^T) * dgelu(a1)   (in-place over a1b)
  gemm6_k<5><<<dim3(8, 508), 256, 0, stream>>>(encden, W2b, nullptr, a1b, nullptr, a1b, NROWS, 1024, 256);
  // 16. db1 partials
  colsum_k<<<dim3(4, 64), 256, 0, stream>>>(a1b, pdb1, 1024);
  // 17. dW1 partials = phi^T @ d_a1 (z=64, balanced staging)
  tgemm5_k<false><<<dim3(2, 8, 64), 256, 0, stream>>>(phi, a1b, pW1, 256, 1024, 256, 1024, NROWS);
  // 18. reduce dW1 + db1
  update1_k<<<1028, 256, 0, stream>>>(pW1, pdb1, W1, b1, W1pT, b1p);
  // 19. buf output (partials consumed)
  bufwrite_k<<<16384, 256, 0, stream>>>(seq, proj, buf);
  // 20. psi = proj @ Wpsi + bpsi
  gemm6_k<1><<<dim3(2, 4), 256, 0, stream>>>(projb, WpsiT, bpsi, psib, nullptr, nullptr, 512, 256, 256);
  // 21. hp = gelu(psi @ W1' + b1')
  gemm6_k<3><<<dim3(8, 4), 256, 0, stream>>>(psib, W1pT, b1p, hpb, nullptr, nullptr, 512, 1024, 256);
  // 22. finb = bf16(hp @ W2' + b2' + contrib)
  gemm6_k<8><<<dim3(2, 4), 256, 0, stream>>>(hpb, W2pT, b2p, finb, nullptr, (const bf16*)contrib, 512, 256, 1024);
  // 24. out = fin @ Wh + h_bias
  gemm6_k<0><<<dim3(2, 4), 256, 0, stream>>>(finb, WhT, hbias, out, nullptr, nullptr, 512, 256, 256);
}

// Round 19
// 859.114 us; speedup vs baseline: 1.0090x; 1.0090x over previous
//
#include <hip/hip_runtime.h>
#include <cmath>

typedef __bf16 bf16;
typedef __attribute__((ext_vector_type(8))) __bf16 bf16x8;
typedef __attribute__((ext_vector_type(4))) __bf16 bf16x4v;
typedef __attribute__((ext_vector_type(4))) float f32x4;
typedef __attribute__((ext_vector_type(2))) unsigned int u32x2;

constexpr int NROWS = 512 * 127;                 // 65024
constexpr float LR = 0.01f;
constexpr float INV_NU = 1.f / (65024.f * 256.f);

// fast (sigmoid) gelu family — |err| < 2e-3 on |x|<1; 27x margin vs threshold.
__device__ __forceinline__ float sigf(float x) {
  return 1.f / (1.f + __expf(-1.702f * x));
}
__device__ __forceinline__ float gelu_fast(float x) { return x * sigf(x); }
__device__ __forceinline__ float dgelu_fast(float x) {
  float s = sigf(x);
  return s * (1.f + 1.702f * x * (1.f - s));
}
__device__ __forceinline__ bf16x8 gelu8f(bf16x8 v) {
  bf16x8 o;
#pragma unroll
  for (int i = 0; i < 8; i++) o[i] = (bf16)gelu_fast((float)v[i]);
  return o;
}

// async global->LDS, 16B per lane, wave-uniform LDS base
__device__ __forceinline__ void gload16(const bf16* g, const bf16* lds) {
  __builtin_amdgcn_global_load_lds(
      (const __attribute__((address_space(1))) unsigned int*)(size_t)(const void*)g,
      (__attribute__((address_space(3))) unsigned int*)(unsigned)(size_t)(const void*)lds,
      16, 0, 0);
}

// XCD chunked-bijective swizzle of the linearized block id (T1).
__device__ __forceinline__ int xcd_lin() {
  int p = ((int)blockIdx.z * (int)gridDim.y + (int)blockIdx.y) * (int)gridDim.x + (int)blockIdx.x;
  const int total = (int)gridDim.x * (int)gridDim.y * (int)gridDim.z;
  if (!(total & 7)) p = (p & 7) * (total >> 3) + (p >> 3);
  return p;
}

// ---------------------------------------------------------------------------
// gemm6: 128x128 tile, BK=32, launch_bounds(256,4) -> total regs <= 128,
// 4 waves/SIMD + 32 KB LDS -> 4 blocks/CU. Double-buffered global_load_lds,
// counted vmcnt(4), XCD swizzle, operand-swapped MFMA -> x4 vector epilogue.
// Chunk swizzle mask(r) = (r&3)^((r>>2)&1): involution, spreads the b128
// reads across all 8 bank slots per 8-lane phase (conflict-free at 64B row
// stride; the plain (r&3) mask left a 2-way conflict).
// EPI: 0=f32, 1=bf16, 2=dgelu->out0+gelu->out1, 3=gelu, 5=acc*dgelu(aux),
//      6=acc*aux, 7=f32 out0 + bf16 out1, 8=bf16(acc + f32 aux)
// ---------------------------------------------------------------------------
template <int EPI>
__global__ __launch_bounds__(256, 4) void gemm6_k(
    const bf16* __restrict__ A, const bf16* __restrict__ Bt,
    const float* __restrict__ bias, void* __restrict__ out0,
    void* __restrict__ out1, const bf16* __restrict__ aux,
    int M, int N, int K) {
  __shared__ __align__(16) bf16 As[2][128 * 32];
  __shared__ __align__(16) bf16 Bs[2][128 * 32];
  const int t = threadIdx.x;
  const int p = xcd_lin();
  const int bn = (p % (int)gridDim.x) * 128;
  const int bm = (p / (int)gridDim.x) * 128;
  const int lane = t & 63, w = t >> 6;
  const int wr = w >> 1, wc = w & 1;

  f32x4 acc[4][4];
#pragma unroll
  for (int mi = 0; mi < 4; mi++)
#pragma unroll
    for (int ni = 0; ni < 4; ni++) {
      f32x4 z = {0.f, 0.f, 0.f, 0.f};
      acc[mi][ni] = z;
    }

  const int lr = lane >> 2;
  const int csw = (lane & 3) ^ (lr & 3) ^ ((lr >> 2) & 1);
  const bf16* aBase = A + (size_t)(bm + 32 * w + lr) * K + csw * 8;
  const bf16* bBase = Bt + (size_t)(bn + 32 * w + lr) * K + csw * 8;

  const int ml = lane & 15, g = lane >> 4;
  const int c0 = g ^ (ml & 3) ^ ((ml >> 2) & 1);

  const int nt = K >> 5;
#pragma unroll
  for (int i = 0; i < 2; i++) {
    gload16(aBase + (size_t)(16 * i) * K, As[0] + (32 * w + 16 * i) * 32);
    gload16(bBase + (size_t)(16 * i) * K, Bs[0] + (32 * w + 16 * i) * 32);
  }

  for (int tt = 0; tt < nt; tt++) {
    const int cur = tt & 1;
    if (tt + 1 < nt) {
      const int ko = (tt + 1) * 32;
#pragma unroll
      for (int i = 0; i < 2; i++) {
        gload16(aBase + (size_t)(16 * i) * K + ko, As[cur ^ 1] + (32 * w + 16 * i) * 32);
        gload16(bBase + (size_t)(16 * i) * K + ko, Bs[cur ^ 1] + (32 * w + 16 * i) * 32);
      }
      asm volatile("s_waitcnt vmcnt(4)" ::: "memory");
    } else {
      asm volatile("s_waitcnt vmcnt(0)" ::: "memory");
    }
    __builtin_amdgcn_s_barrier();
    __builtin_amdgcn_sched_barrier(0);

    bf16x8 af[4], bfr[4];
#pragma unroll
    for (int mi = 0; mi < 4; mi++) {
      const int m = wr * 64 + mi * 16 + ml;
      const int n = wc * 64 + mi * 16 + ml;
      af[mi] = *(const bf16x8*)&As[cur][m * 32 + c0 * 8];
      bfr[mi] = *(const bf16x8*)&Bs[cur][n * 32 + c0 * 8];
    }
#pragma unroll
    for (int mi = 0; mi < 4; mi++)
#pragma unroll
      for (int ni = 0; ni < 4; ni++)
        acc[mi][ni] = __builtin_amdgcn_mfma_f32_16x16x32_bf16(
            bfr[ni], af[mi], acc[mi][ni], 0, 0, 0);
    __builtin_amdgcn_s_barrier();
  }

  const int g4 = (lane >> 4) << 2;
#pragma unroll
  for (int mi = 0; mi < 4; mi++) {
    const int m = bm + wr * 64 + mi * 16 + ml;
#pragma unroll
    for (int ni = 0; ni < 4; ni++) {
      const int n0 = bn + wc * 64 + ni * 16 + g4;
      f32x4 v = acc[mi][ni];
      if (bias) {
        const float4 bv = *(const float4*)(bias + n0);
        v[0] += bv.x; v[1] += bv.y; v[2] += bv.z; v[3] += bv.w;
      }
      const size_t idx = (size_t)m * N + n0;
      if constexpr (EPI == 0) {
        *(float4*)((float*)out0 + idx) = make_float4(v[0], v[1], v[2], v[3]);
      } else if constexpr (EPI == 1) {
        bf16x4v o;
#pragma unroll
        for (int j = 0; j < 4; j++) o[j] = (bf16)v[j];
        *(bf16x4v*)((bf16*)out0 + idx) = o;
      } else if constexpr (EPI == 2) {
        bf16x4v od, oh;
#pragma unroll
        for (int j = 0; j < 4; j++) {
          float s = sigf(v[j]);
          oh[j] = (bf16)(v[j] * s);
          od[j] = (bf16)(s * (1.f + 1.702f * v[j] * (1.f - s)));
        }
        *(bf16x4v*)((bf16*)out0 + idx) = od;
        *(bf16x4v*)((bf16*)out1 + idx) = oh;
      } else if constexpr (EPI == 3) {
        bf16x4v o;
#pragma unroll
        for (int j = 0; j < 4; j++) o[j] = (bf16)gelu_fast(v[j]);
        *(bf16x4v*)((bf16*)out0 + idx) = o;
      } else if constexpr (EPI == 5) {
        const bf16x4v a4 = *(const bf16x4v*)(aux + idx);
        bf16x4v o;
#pragma unroll
        for (int j = 0; j < 4; j++) o[j] = (bf16)(v[j] * dgelu_fast((float)a4[j]));
        *(bf16x4v*)((bf16*)out0 + idx) = o;
      } else if constexpr (EPI == 6) {
        const bf16x4v a4 = *(const bf16x4v*)(aux + idx);
        bf16x4v o;
#pragma unroll
        for (int j = 0; j < 4; j++) o[j] = (bf16)(v[j] * (float)a4[j]);
        *(bf16x4v*)((bf16*)out0 + idx) = o;
      } else if constexpr (EPI == 7) {
        *(float4*)((float*)out0 + idx) = make_float4(v[0], v[1], v[2], v[3]);
        bf16x4v o;
#pragma unroll
        for (int j = 0; j < 4; j++) o[j] = (bf16)v[j];
        *(bf16x4v*)((bf16*)out1 + idx) = o;
      } else {   // EPI 8
        const float4 c4 = *(const float4*)((const float*)aux + idx);
        bf16x4v o;
        o[0] = (bf16)(v[0] + c4.x); o[1] = (bf16)(v[1] + c4.y);
        o[2] = (bf16)(v[2] + c4.z); o[3] = (bf16)(v[3] + c4.w);
        *(bf16x4v*)((bf16*)out0 + idx) = o;
      }
    }
  }
}

// ---------------------------------------------------------------------------
// gemm7: gemm6 structure, A reg-staged with fast-gelu applied once at the
// write-late LDS store. B keeps global_load_lds. Same improved swizzle.
// Used for z = gelu(a1) @ Wzg + bzg.
// ---------------------------------------------------------------------------
template <int EPI>
__global__ __launch_bounds__(256, 4) void gemm7_k(
    const bf16* __restrict__ A, const bf16* __restrict__ Bt,
    const float* __restrict__ bias, void* __restrict__ out0,
    void* __restrict__ out1, const bf16* __restrict__ aux,
    int M, int N, int K) {
  __shared__ __align__(16) bf16 As[2][128 * 32];
  __shared__ __align__(16) bf16 Bs[2][128 * 32];
  const int t = threadIdx.x;
  const int p = xcd_lin();
  const int bn = (p % (int)gridDim.x) * 128;
  const int bm = (p / (int)gridDim.x) * 128;
  const int lane = t & 63, w = t >> 6;
  const int wr = w >> 1, wc = w & 1;

  f32x4 acc[4][4];
#pragma unroll
  for (int mi = 0; mi < 4; mi++)
#pragma unroll
    for (int ni = 0; ni < 4; ni++) {
      f32x4 z = {0.f, 0.f, 0.f, 0.f};
      acc[mi][ni] = z;
    }

  const int lr = lane >> 2;
  const int csw = (lane & 3) ^ (lr & 3) ^ ((lr >> 2) & 1);
  const bf16* aBase = A + (size_t)(bm + 32 * w + lr) * K + csw * 8;
  const bf16* bBase = Bt + (size_t)(bn + 32 * w + lr) * K + csw * 8;
  const int awoff = (32 * w + lr) * 32 + (lane & 3) * 8;

  const int ml = lane & 15, g = lane >> 4;
  const int c0 = g ^ (ml & 3) ^ ((ml >> 2) & 1);

  const int nt = K >> 5;
  {
    bf16x8 av0 = *(const bf16x8*)aBase;
    bf16x8 av1 = *(const bf16x8*)(aBase + (size_t)16 * K);
    gload16(bBase, Bs[0] + (32 * w) * 32);
    gload16(bBase + (size_t)16 * K, Bs[0] + (32 * w + 16) * 32);
    *(bf16x8*)&As[0][awoff] = gelu8f(av0);
    *(bf16x8*)&As[0][awoff + 512] = gelu8f(av1);
  }
  __syncthreads();

  bf16x8 av0, av1;
  for (int tt = 0; tt < nt; tt++) {
    const int cur = tt & 1;
    if (tt + 1 < nt) {
      const int ko = (tt + 1) * 32;
      gload16(bBase + ko, Bs[cur ^ 1] + (32 * w) * 32);
      gload16(bBase + (size_t)16 * K + ko, Bs[cur ^ 1] + (32 * w + 16) * 32);
      av0 = *(const bf16x8*)(aBase + ko);
      av1 = *(const bf16x8*)(aBase + (size_t)16 * K + ko);
    }

    bf16x8 af[4], bfr[4];
#pragma unroll
    for (int mi = 0; mi < 4; mi++) {
      const int m = wr * 64 + mi * 16 + ml;
      const int n = wc * 64 + mi * 16 + ml;
      af[mi] = *(const bf16x8*)&As[cur][m * 32 + c0 * 8];
      bfr[mi] = *(const bf16x8*)&Bs[cur][n * 32 + c0 * 8];
    }
#pragma unroll
    for (int mi = 0; mi < 4; mi++)
#pragma unroll
      for (int ni = 0; ni < 4; ni++)
        acc[mi][ni] = __builtin_amdgcn_mfma_f32_16x16x32_bf16(
            bfr[ni], af[mi], acc[mi][ni], 0, 0, 0);

    if (tt + 1 < nt) {
      *(bf16x8*)&As[cur ^ 1][awoff] = gelu8f(av0);
      *(bf16x8*)&As[cur ^ 1][awoff + 512] = gelu8f(av1);
    }
    __syncthreads();
  }

  const int g4 = (lane >> 4) << 2;
#pragma unroll
  for (int mi = 0; mi < 4; mi++) {
    const int m = bm + wr * 64 + mi * 16 + ml;
#pragma unroll
    for (int ni = 0; ni < 4; ni++) {
      const int n0 = bn + wc * 64 + ni * 16 + g4;
      f32x4 v = acc[mi][ni];
      if (bias) {
        const float4 bv = *(const float4*)(bias + n0);
        v[0] += bv.x; v[1] += bv.y; v[2] += bv.z; v[3] += bv.w;
      }
      const size_t idx = (size_t)m * N + n0;
      if constexpr (EPI == 0) {
        *(float4*)((float*)out0 + idx) = make_float4(v[0], v[1], v[2], v[3]);
      } else {
        bf16x4v o;
#pragma unroll
        for (int j = 0; j < 4; j++) o[j] = (bf16)v[j];
        *(bf16x4v*)((bf16*)out0 + idx) = o;
      }
    }
  }
}

// ---------------------------------------------------------------------------
// T-GEMM v4 (round-17 measured-best): tr_b16 transpose reads, subtiled LDS,
// double-buffered, load-early/write-late, one __syncthreads per iter.
// ---------------------------------------------------------------------------
template <bool GELU_A>
__global__ __launch_bounds__(256) void tgemm4_k(
    const bf16* __restrict__ Asrc, const bf16* __restrict__ Bsrc,
    float* __restrict__ outP, int M, int N, int ldA, int ldB, int K) {
  __shared__ __align__(16) bf16 As[2][4736];
  __shared__ __align__(16) bf16 Bs[2][4736];
  const int t = threadIdx.x;
  const int p = xcd_lin();
  const int gx = (int)gridDim.x, gy = (int)gridDim.y;
  const int bm = (p % gx) * 128;
  const int bn = ((p / gx) % gy) * 128;
  const int zc = p / (gx * gy);
  const int r0 = zc * 1024;
  const int rows = (K - r0 < 1024) ? (K - r0) : 1024;
  const int nt = rows >> 5;
  const int lane = t & 63, w = t >> 6, wr = w >> 1, wc = w & 1;

  f32x4 acc[4][4];
#pragma unroll
  for (int mi = 0; mi < 4; mi++)
#pragma unroll
    for (int ni = 0; ni < 4; ni++) {
      f32x4 z = {0.f, 0.f, 0.f, 0.f};
      acc[mi][ni] = z;
    }

  const bool isB = t >= 128;
  const int srow = (t & 127) >> 4;
  const int scol = (t & 15) * 8;
  const int sms = (t & 15) >> 1;
  const int shalf = (t & 1) * 8;
  const bf16* src = isB ? Bsrc : Asrc;
  const int ld = isB ? ldB : ldA;
  const int bx = isB ? bn : bm;
  const int sidx = sms * 592 + srow * 16 + shalf;

  const unsigned abase = (unsigned)(size_t)(void*)As;
  const unsigned bbase = (unsigned)(size_t)(void*)Bs;
  const int g = lane >> 4;
  const int ml = lane & 15;
  const unsigned acol0 = abase + 2u * (unsigned)((wr * 4) * 592 + g * 144 + ml);
  const unsigned bcol0 = bbase + 2u * (unsigned)((wc * 4) * 592 + g * 144 + ml);

  auto ldrow = [&](int kt, int ll) {
    return *(const bf16x8*)(src + (size_t)(r0 + kt + srow + ll * 8) * ld + bx + scol);
  };
  auto wrbuf = [&](bf16* dst, bf16x8* stg) {
#pragma unroll
    for (int ll = 0; ll < 4; ll++) {
      bf16x8 v = stg[ll];
      if constexpr (GELU_A) { if (!isB) v = gelu8f(v); }
      *(bf16x8*)&dst[sidx + ll * 144] = v;
    }
  };

  bf16x8 stg[4];
#pragma unroll
  for (int ll = 0; ll < 4; ll++) stg[ll] = ldrow(0, ll);
  wrbuf(isB ? Bs[0] : As[0], stg);
  __syncthreads();

  for (int tt = 0; tt < nt; tt++) {
    const int cur = tt & 1;
    if (tt + 1 < nt) {
#pragma unroll
      for (int ll = 0; ll < 4; ll++) stg[ll] = ldrow((tt + 1) * 32, ll);
    }
    const unsigned boff = (unsigned)cur * (4736u * 2u);
    union FR { u32x2 pr[2]; bf16x8 v; };
    FR af[4], bfr[4];
#pragma unroll
    for (int mi = 0; mi < 4; mi++) {
      const unsigned a = acol0 + boff + (unsigned)(mi * 1184);
      asm volatile("ds_read_b64_tr_b16 %0, %1" : "=v"(af[mi].pr[0]) : "v"(a));
      asm volatile("ds_read_b64_tr_b16 %0, %1 offset:128" : "=v"(af[mi].pr[1]) : "v"(a));
    }
#pragma unroll
    for (int ni = 0; ni < 4; ni++) {
      const unsigned b = bcol0 + boff + (unsigned)(ni * 1184);
      asm volatile("ds_read_b64_tr_b16 %0, %1" : "=v"(bfr[ni].pr[0]) : "v"(b));
      asm volatile("ds_read_b64_tr_b16 %0, %1 offset:128" : "=v"(bfr[ni].pr[1]) : "v"(b));
    }
    asm volatile("s_waitcnt lgkmcnt(0)" ::: "memory");
    __builtin_amdgcn_sched_barrier(0);

#pragma unroll
    for (int mi = 0; mi < 4; mi++)
#pragma unroll
      for (int ni = 0; ni < 4; ni++)
        acc[mi][ni] = __builtin_amdgcn_mfma_f32_16x16x32_bf16(
            bfr[ni].v, af[mi].v, acc[mi][ni], 0, 0, 0);

    if (tt + 1 < nt) wrbuf(isB ? Bs[cur ^ 1] : As[cur ^ 1], stg);
    __syncthreads();
  }

  float* o = outP + (size_t)zc * M * N;
  const int g4 = (lane >> 4) << 2;
#pragma unroll
  for (int mi = 0; mi < 4; mi++) {
    const int m = bm + wr * 64 + mi * 16 + ml;
#pragma unroll
    for (int ni = 0; ni < 4; ni++) {
      const int n0 = bn + wc * 64 + ni * 16 + g4;
      f32x4 v = acc[mi][ni];
      *(float4*)(o + (size_t)m * N + n0) = make_float4(v[0], v[1], v[2], v[3]);
    }
  }
}

// ---------------------------------------------------------------------------
__global__ void prep_k(const float* inputs, const float* Wp, const float* Wphi,
                       const float* W1, const float* W2, const float* Wg,
                       const float* Wpsi, const float* Wh,
                       bf16* inb, bf16* WpT, bf16* WphiT, bf16* W1T, bf16* W2T,
                       bf16* WgT, bf16* Wgb, bf16* W2b, bf16* WpsiT, bf16* WhT) {
  int i = blockIdx.x * 256 + threadIdx.x;
  if (i < 65536) {
    inb[i] = (bf16)inputs[i];
  } else if ((i -= 65536) < 32768) {
    int u = i >> 7, f = i & 127;
    WpT[i] = (bf16)Wp[f * 256 + u];
  } else if ((i -= 32768) < 65536) {
    int n = i >> 8, k = i & 255;
    WphiT[i] = (bf16)Wphi[k * 256 + n];
  } else if ((i -= 65536) < 262144) {
    int h = i >> 8, u = i & 255;
    W1T[i] = (bf16)W1[u * 1024 + h];
  } else if ((i -= 262144) < 262144) {
    int u = i >> 10, h = i & 1023;
    W2T[i] = (bf16)W2[h * 256 + u];
  } else if ((i -= 262144) < 65536) {
    int n = i >> 8, k = i & 255;
    WgT[i] = (bf16)Wg[k * 256 + n];
  } else if ((i -= 65536) < 65536) {
    Wgb[i] = (bf16)Wg[i];
  } else if ((i -= 65536) < 262144) {
    W2b[i] = (bf16)W2[i];
  } else if ((i -= 262144) < 65536) {
    int n = i >> 8, k = i & 255;
    WpsiT[i] = (bf16)Wpsi[k * 256 + n];
  } else if ((i -= 65536) < 65536) {
    int n = i >> 8, k = i & 255;
    WhT[i] = (bf16)Wh[k * 256 + n];
  }
}

// bzg[n] = gbias[n] + sum_j b2[j] * Wg[j][n]
__global__ void bzg_k(const float* __restrict__ b2, const float* __restrict__ Wg,
                      const float* __restrict__ gbias, float* __restrict__ bzg) {
  const int n = threadIdx.x;
  float s = gbias[n];
  for (int j = 0; j < 256; j++) s += b2[j] * Wg[j * 256 + n];
  bzg[n] = s;
}

__global__ void xcast_k(const float* __restrict__ seq, bf16* __restrict__ xb) {
  int v8 = blockIdx.x * 256 + threadIdx.x;
  int r = v8 >> 5, c8 = (v8 & 31) * 8;
  int b = r / 127, t = r - b * 127;
  const float* src = seq + ((size_t)(b * 128 + t + 1)) * 256 + c8;
  float4 v0 = *(const float4*)(src);
  float4 v1 = *(const float4*)(src + 4);
  bf16x8 o;
  o[0] = (bf16)v0.x; o[1] = (bf16)v0.y; o[2] = (bf16)v0.z; o[3] = (bf16)v0.w;
  o[4] = (bf16)v1.x; o[5] = (bf16)v1.y; o[6] = (bf16)v1.z; o[7] = (bf16)v1.w;
  *(bf16x8*)(xb + (size_t)r * 256 + c8) = o;
}

__global__ void bufwrite_k(const float* __restrict__ seq, const float* __restrict__ proj,
                           float* __restrict__ buf) {
  int i = blockIdx.x * 256 + threadIdx.x;
  int b = i >> 13, rem = i & 8191;
  int j = rem >> 6, c4 = (rem & 63) * 4;
  float4 v;
  if (j < 127)
    v = *(const float4*)(seq + ((size_t)(b * 128 + j + 1)) * 256 + c4);
  else
    v = *(const float4*)(proj + (size_t)b * 256 + c4);
  *(float4*)(buf + ((size_t)(b * 128 + j)) * 256 + c4) = v;
}

__global__ __launch_bounds__(256) void ln_k(const bf16* zin, bf16* dzout,
                                            const float* __restrict__ seq,
                                            const float* __restrict__ proj,
                                            const float* __restrict__ lng,
                                            const float* __restrict__ lnb,
                                            bf16* __restrict__ rec) {
  const int w = threadIdx.x >> 6, lane = threadIdx.x & 63;
  const int r = blockIdx.x * 4 + w;
  const int b = r / 127, tt = r - b * 127;
  typedef __attribute__((ext_vector_type(4))) __bf16 bf16x4;
  bf16x4 zv = *(const bf16x4*)(zin + (size_t)r * 256 + lane * 4);
  float z0 = (float)zv[0], z1 = (float)zv[1], z2 = (float)zv[2], z3 = (float)zv[3];
  float s1 = z0 + z1 + z2 + z3;
  float s2 = z0 * z0 + z1 * z1 + z2 * z2 + z3 * z3;
  for (int m = 1; m < 64; m <<= 1) { s1 += __shfl_xor(s1, m); s2 += __shfl_xor(s2, m); }
  const float mean = s1 * (1.f / 256.f);
  const float var = s2 * (1.f / 256.f) - mean * mean;
  const float rs = rsqrtf(var + 1e-3f);
  const float4 gv = *(const float4*)(lng + lane * 4);
  const float4 bv = *(const float4*)(lnb + lane * 4);
  const float* ysrc = (tt < 126) ? (seq + ((size_t)(b * 128 + tt + 2)) * 256)
                                 : (proj + (size_t)b * 256);
  const float4 yv = *(const float4*)(ysrc + lane * 4);
  float xh0 = (z0 - mean) * rs, xh1 = (z1 - mean) * rs, xh2 = (z2 - mean) * rs, xh3 = (z3 - mean) * rs;
  float r0 = gv.x * xh0 + bv.x, r1 = gv.y * xh1 + bv.y, r2 = gv.z * xh2 + bv.z, r3 = gv.w * xh3 + bv.w;
  float u0 = 2.f * (r0 - yv.x) * INV_NU * gv.x;
  float u1 = 2.f * (r1 - yv.y) * INV_NU * gv.y;
  float u2 = 2.f * (r2 - yv.z) * INV_NU * gv.z;
  float u3 = 2.f * (r3 - yv.w) * INV_NU * gv.w;
  float t1 = u0 + u1 + u2 + u3;
  float t2 = u0 * xh0 + u1 * xh1 + u2 * xh2 + u3 * xh3;
  for (int m = 1; m < 64; m <<= 1) { t1 += __shfl_xor(t1, m); t2 += __shfl_xor(t2, m); }
  const float mu = t1 * (1.f / 256.f), mux = t2 * (1.f / 256.f);
  bf16x4 ro, dzo;
  ro[0] = (bf16)r0; ro[1] = (bf16)r1; ro[2] = (bf16)r2; ro[3] = (bf16)r3;
  dzo[0] = (bf16)((u0 - mu - xh0 * mux) * rs);
  dzo[1] = (bf16)((u1 - mu - xh1 * mux) * rs);
  dzo[2] = (bf16)((u2 - mu - xh2 * mux) * rs);
  dzo[3] = (bf16)((u3 - mu - xh3 * mux) * rs);
  *(bf16x4*)(rec + (size_t)r * 256 + lane * 4) = ro;
  *(bf16x4*)(dzout + (size_t)r * 256 + lane * 4) = dzo;
}

__global__ void colsum_k(const bf16* __restrict__ src, float* __restrict__ part, int C) {
  const int col = blockIdx.x * 256 + threadIdx.x;
  const int ch = blockIdx.y;
  float s = 0.f;
  const int rbeg = ch * 1016;
  for (int rr = rbeg; rr < rbeg + 1016; rr++) s += (float)src[(size_t)rr * C + col];
  part[(size_t)ch * C + col] = s;
}

__global__ void contrib_k(const bf16* __restrict__ rec, float* __restrict__ contrib) {
  const int b = blockIdx.x, u = threadIdx.x;
  float s = 0.f;
  for (int t = 0; t < 127; t++) s += (float)rec[((size_t)b * 127 + t) * 256 + u];
  contrib[b * 256 + u] = s * (1.f / 127.f);
}

__global__ void update2_k(const float* __restrict__ pW2, const float* __restrict__ pdb2,
                          const float* __restrict__ W2, const float* __restrict__ b2,
                          bf16* __restrict__ W2pT, float* __restrict__ b2p) {
  int idx = blockIdx.x * 256 + threadIdx.x;
  if (idx < 262144) {
    float s = 0.f;
    for (int z = 0; z < 64; z++) s += pW2[(size_t)z * 262144 + idx];
    int h = idx >> 8, u = idx & 255;
    W2pT[(size_t)u * 1024 + h] = (bf16)(W2[idx] - LR * s);
  } else {
    int u = idx - 262144;
    float s = 0.f;
    for (int c = 0; c < 64; c++) s += pdb2[c * 256 + u];
    b2p[u] = b2[u] - LR * s;
  }
}

__global__ void update1_k(const float* __restrict__ pW1, const float* __restrict__ pdb1,
                          const float* __restrict__ W1, const float* __restrict__ b1,
                          bf16* __restrict__ W1pT, float* __restrict__ b1p) {
  int idx = blockIdx.x * 256 + threadIdx.x;
  if (idx < 262144) {
    float s = 0.f;
    for (int z = 0; z < 64; z++) s += pW1[(size_t)z * 262144 + idx];
    int u = idx >> 10, h = idx & 1023;
    W1pT[(size_t)h * 256 + u] = (bf16)(W1[idx] - LR * s);
  } else {
    int h = idx - 262144;
    float s = 0.f;
    for (int c = 0; c < 64; c++) s += pdb1[c * 1024 + h];
    b1p[h] = b1[h] - LR * s;
  }
}

// ---------------------------------------------------------------------------
extern "C" void kernel_launch(void* const* d_in, const int* in_sizes, int n_in,
                              void* d_out, int out_size, void* d_ws, size_t ws_size,
                              hipStream_t stream) {
  const float* inputs = (const float*)d_in[0];
  const float* seq = (const float*)d_in[2];
  const float* Wp = (const float*)d_in[3];
  const float* bp = (const float*)d_in[4];
  const float* Wphi = (const float*)d_in[5];
  const float* bphi = (const float*)d_in[6];
  const float* Wpsi = (const float*)d_in[7];
  const float* bpsi = (const float*)d_in[8];
  const float* W1 = (const float*)d_in[9];
  const float* b1 = (const float*)d_in[10];
  const float* W2 = (const float*)d_in[11];
  const float* b2 = (const float*)d_in[12];
  const float* Wg = (const float*)d_in[13];
  const float* gbias = (const float*)d_in[14];
  const float* lng = (const float*)d_in[15];
  const float* lnb = (const float*)d_in[16];
  const float* Wh = (const float*)d_in[17];
  const float* hbias = (const float*)d_in[18];

  float* out = (float*)d_out;
  float* buf = out + 131072;
  float* pW2 = buf;                          // 64 x 262144 f32 (fills buf)
  float* pW1 = buf;                          // same region, sequential use

  char* wptr = (char*)d_ws;
  auto alloc = [&](size_t bytes) {
    char* p = wptr;
    wptr += (bytes + 255) & ~(size_t)255;
    return p;
  };
  bf16* inb   = (bf16*)alloc(65536 * 2);
  bf16* WpT   = (bf16*)alloc(32768 * 2);
  bf16* WphiT = (bf16*)alloc(65536 * 2);
  bf16* W1T   = (bf16*)alloc(262144 * 2);
  bf16* W2T   = (bf16*)alloc(262144 * 2);
  bf16* WgT   = (bf16*)alloc(65536 * 2);
  bf16* Wgb   = (bf16*)alloc(65536 * 2);
  bf16* W2b   = (bf16*)alloc(262144 * 2);
  bf16* WpsiT = (bf16*)alloc(65536 * 2);
  bf16* WhT   = (bf16*)alloc(65536 * 2);
  bf16* WzgT  = (bf16*)alloc(262144 * 2);
  float* bzg  = (float*)alloc(256 * 4);
  bf16* W1pT  = (bf16*)alloc(262144 * 2);
  bf16* W2pT  = (bf16*)alloc(262144 * 2);
  float* b1p  = (float*)alloc(1024 * 4);
  float* b2p  = (float*)alloc(256 * 4);
  float* proj = (float*)alloc(131072 * 4);
  bf16* projb = (bf16*)alloc(131072 * 2);
  float* pdb2 = (float*)alloc(64 * 256 * 4);
  float* pdb1 = (float*)alloc(64 * 1024 * 4);
  bf16* psib  = (bf16*)alloc(131072 * 2);
  bf16* hpb   = (bf16*)alloc(524288 * 2);
  float* contrib = (float*)alloc(131072 * 4);
  bf16* finb  = (bf16*)alloc(131072 * 2);
  const size_t NU = (size_t)NROWS * 256;
  const size_t NH = (size_t)NROWS * 1024;
  bf16* xz     = (bf16*)alloc(NU * 2);       // x -> z -> dz
  bf16* phi    = (bf16*)alloc(NU * 2);
  bf16* a1b    = (bf16*)alloc(NH * 2);       // a1 -> da1
  bf16* encden = (bf16*)alloc(NU * 2);       // rec -> denc

  // 1. prep weights (+inputs cast)
  prep_k<<<4736, 256, 0, stream>>>(inputs, Wp, Wphi, W1, W2, Wg, Wpsi, Wh,
                                   inb, WpT, WphiT, W1T, W2T, WgT, Wgb, W2b, WpsiT, WhT);
  // 1b. WzgT = Wg^T @ W2^T
  gemm6_k<1><<<dim3(8, 2), 256, 0, stream>>>(WgT, W2b, nullptr, WzgT, nullptr, nullptr, 256, 1024, 256);
  // 1c. bzg = b2 @ Wg + gbias
  bzg_k<<<1, 256, 0, stream>>>(b2, Wg, gbias, bzg);
  // 2. x = bf16(seq shifted)
  xcast_k<<<8128, 256, 0, stream>>>(seq, xz);
  // 3. proj = inputs @ Wp + bp  (f32 + bf16 dual store)
  gemm6_k<7><<<dim3(2, 4), 256, 0, stream>>>(inb, WpT, bp, proj, projb, nullptr, 512, 256, 128);
  // 5. phi = x @ Wphi + bphi
  gemm6_k<1><<<dim3(2, 508), 256, 0, stream>>>(xz, WphiT, bphi, phi, nullptr, nullptr, NROWS, 256, 256);
  // 6. a1 = phi @ W1 + b1   (a1 only; consumers recompute gelu/dgelu)
  gemm6_k<1><<<dim3(8, 508), 256, 0, stream>>>(phi, W1T, b1, a1b, nullptr, nullptr, NROWS, 1024, 256);
  // 7+8 fused. z = gelu(a1) @ (W2@Wg) + bzg   (gelu once in reg staging)
  gemm7_k<1><<<dim3(2, 508), 256, 0, stream>>>(a1b, WzgT, bzg, xz, nullptr, nullptr, NROWS, 256, 1024);
  // 9. LN fwd+bwd: rec -> encden, dz in-place in xz
  ln_k<<<16256, 256, 0, stream>>>(xz, xz, seq, proj, lng, lnb, encden);
  // 10. contrib = mean_t rec
  contrib_k<<<512, 256, 0, stream>>>(encden, contrib);
  // 11. d_enc = dz @ Wg^T (into encden)
  gemm6_k<1><<<dim3(2, 508), 256, 0, stream>>>(xz, Wgb, nullptr, encden, nullptr, nullptr, NROWS, 256, 256);
  // 12. db2 partials
  colsum_k<<<dim3(1, 64), 256, 0, stream>>>(encden, pdb2, 256);
  // 13. dW2 partials = gelu(a1)^T @ d_enc (z=64, gelu in staging)
  tgemm4_k<true><<<dim3(8, 2, 64), 256, 0, stream>>>(a1b, encden, pW2, 1024, 256, 1024, 256, NROWS);
  // 14. reduce dW2 + db2
  update2_k<<<1025, 256, 0, stream>>>(pW2, pdb2, W2, b2, W2pT, b2p);
  // 15. d_a1 = (d_enc @ W2^T) * dgelu(a1)   (in-place over a1b)
  gemm6_k<5><<<dim3(8, 508), 256, 0, stream>>>(encden, W2b, nullptr, a1b, nullptr, a1b, NROWS, 1024, 256);
  // 16. db1 partials
  colsum_k<<<dim3(4, 64), 256, 0, stream>>>(a1b, pdb1, 1024);
  // 17. dW1 partials = phi^T @ d_a1 (z=64)
  tgemm4_k<false><<<dim3(2, 8, 64), 256, 0, stream>>>(phi, a1b, pW1, 256, 1024, 256, 1024, NROWS);
  // 18. reduce dW1 + db1
  update1_k<<<1028, 256, 0, stream>>>(pW1, pdb1, W1, b1, W1pT, b1p);
  // 19. buf output (partials consumed)
  bufwrite_k<<<16384, 256, 0, stream>>>(seq, proj, buf);
  // 20. psi = proj @ Wpsi + bpsi
  gemm6_k<1><<<dim3(2, 4), 256, 0, stream>>>(projb, WpsiT, bpsi, psib, nullptr, nullptr, 512, 256, 256);
  // 21. hp = gelu(psi @ W1' + b1')
  gemm6_k<3><<<dim3(8, 4), 256, 0, stream>>>(psib, W1pT, b1p, hpb, nullptr, nullptr, 512, 1024, 256);
  // 22. finb = bf16(hp @ W2' + b2' + contrib)
  gemm6_k<8><<<dim3(2, 4), 256, 0, stream>>>(hpb, W2pT, b2p, finb, nullptr, (const bf16*)contrib, 512, 256, 1024);
  // 24. out = fin @ Wh + h_bias
  gemm6_k<0><<<dim3(2, 4), 256, 0, stream>>>(finb, WhT, hbias, out, nullptr, nullptr, 512, 256, 256);
}